// Round 7
// baseline (494.990 us; speedup 1.0000x reference)
//
#include <hip/hip_runtime.h>

#define B_ 4096
#define T_ 512
#define F_ 8
#define H_ 16

typedef _Float16 h2 __attribute__((ext_vector_type(2)));

#define L2E 1.44269504088896340736f

__device__ __forceinline__ float rcpf_(float x) { return __builtin_amdgcn_rcpf(x); }
__device__ __forceinline__ float exp2f_(float x) { return __builtin_amdgcn_exp2f(x); }

__device__ __forceinline__ float fdot2_(h2 a, h2 b, float c) {
#if __has_builtin(__builtin_amdgcn_fdot2)
    return __builtin_amdgcn_fdot2(a, b, c, false);
#else
    return c + (float)a[0] * (float)b[0] + (float)a[1] * (float)b[1];
#endif
}

#if __has_builtin(__builtin_amdgcn_update_dpp)
#define DPPX(v, ctrl) __builtin_bit_cast(float, __builtin_amdgcn_update_dpp( \
    0, __builtin_bit_cast(int, (v)), (ctrl), 0xF, 0xF, true))
__device__ __forceinline__ float dpp_x1(float v) { return DPPX(v, 0xB1); } // quad xor 1
__device__ __forceinline__ float dpp_x2(float v) { return DPPX(v, 0x4E); } // quad xor 2
__device__ __forceinline__ float dpp_x3(float v) { return DPPX(v, 0x1B); } // quad xor 3
#else
__device__ __forceinline__ float dpp_x1(float v) { return __shfl_xor(v, 1); }
__device__ __forceinline__ float dpp_x2(float v) { return __shfl_xor(v, 2); }
__device__ __forceinline__ float dpp_x3(float v) { return __shfl_xor(v, 3); }
#endif

__device__ __forceinline__ h2 bch2(unsigned u) { return __builtin_bit_cast(h2, u); }

// One WAVE per chain; lane: gate g=lane&3 (0=i,1=f,2=g,3=o), unit j=lane>>2,
// weight row r=g*16+j. Weights/h/x in f16; dots via v_dot2_f32_f16 (f32 acc).
// Rows prescaled: sigmoid rows by -log2e, tanh row by +2log2e -> uniform
// activation rcp(1+exp2(gate))*mA+mB. Quad gate-gather via DPP quad_perm.
// h broadcast: packed-f16 LDS region per g (48B stride), 1 b16 write + 2
// broadcast b128 reads. Encoder x: 32-step chunks staged to LDS as f16,
// double-buffered, full 32-unroll -> all LDS offsets immediate.
__global__ __launch_bounds__(64, 4) void lstm_ae_w64(
    const float* __restrict__ x,
    const float* __restrict__ eWih, const float* __restrict__ eWhh,
    const float* __restrict__ ebih, const float* __restrict__ ebhh,
    const float* __restrict__ dWih, const float* __restrict__ dWhh,
    const float* __restrict__ dbih, const float* __restrict__ dbhh,
    const float* __restrict__ oW,   const float* __restrict__ ob,
    float* __restrict__ out)
{
    const int lane = threadIdx.x;
    const int g = lane & 3;
    const int j = lane >> 2;
    const int r = g * 16 + j;
    const int chain = blockIdx.x;

    __shared__ __align__(16) _Float16 hsh[4 * 24];   // 4 regions x 24 halves
    __shared__ __align__(16) _Float16 xsA[256];      // 32 steps x 8 feats, f16
    __shared__ __align__(16) _Float16 xsB[256];

    const float sG = (g == 2) ? (2.0f * L2E) : (-L2E);
    const float mA = (g == 2) ? -2.0f : 1.0f;
    const float mB = (g == 2) ? 1.0f : 0.0f;
    const bool gb0 = (g & 1) != 0, gb1 = (g & 2) != 0;

    // ---- encoder weights (prescaled f16 pairs) ----
    h2 wh[8], wiH[4];
#pragma unroll
    for (int k = 0; k < 8; ++k)
        wh[k] = h2{(_Float16)(sG * eWhh[r * 16 + 2 * k]),
                   (_Float16)(sG * eWhh[r * 16 + 2 * k + 1])};
#pragma unroll
    for (int k = 0; k < 4; ++k)
        wiH[k] = h2{(_Float16)(sG * eWih[r * 8 + 2 * k]),
                    (_Float16)(sG * eWih[r * 8 + 2 * k + 1])};
    const float ebias = sG * (ebih[r] + ebhh[r]);

    const float* xb = x + (size_t)chain * (T_ * F_);

    // stage chunk 0 (f16), prefetch chunk 1
    {
        const float4 v = *(const float4*)(xb + lane * 4);
        uint2 p;
        p.x = __builtin_bit_cast(unsigned, h2{(_Float16)v.x, (_Float16)v.y});
        p.y = __builtin_bit_cast(unsigned, h2{(_Float16)v.z, (_Float16)v.w});
        *(uint2*)(xsA + lane * 4) = p;
    }
    float4 pf = *(const float4*)(xb + 256 + lane * 4);

    hsh[g * 24 + j] = (_Float16)0.f;
    h2 hx[8];
#pragma unroll
    for (int p = 0; p < 8; ++p) hx[p] = h2{(_Float16)0.f, (_Float16)0.f};
    float c = 0.f;

    // xp for step 0
    float xp;
    {
        const uint4 u = *(const uint4*)(xsA);
        float aa = fdot2_(wiH[0], bch2(u.x), ebias);
        float bb = fdot2_(wiH[1], bch2(u.y), 0.f);
        aa = fdot2_(wiH[2], bch2(u.z), aa);
        bb = fdot2_(wiH[3], bch2(u.w), bb);
        xp = aa + bb;
    }

    // ---------------- encoder ----------------
    for (int chunk = 0; chunk < 16; ++chunk) {
        const _Float16* xc = (chunk & 1) ? xsB : xsA;
#pragma unroll
        for (int s = 0; s < 32; ++s) {
            float aa = fdot2_(wh[0], hx[0], xp);
            float bb = fdot2_(wh[1], hx[1], 0.f);
            aa = fdot2_(wh[2], hx[2], aa);
            bb = fdot2_(wh[3], hx[3], bb);
            aa = fdot2_(wh[4], hx[4], aa);
            bb = fdot2_(wh[5], hx[5], bb);
            aa = fdot2_(wh[6], hx[6], aa);
            bb = fdot2_(wh[7], hx[7], bb);
            const float gate = aa + bb;

            const float act = __builtin_fmaf(rcpf_(1.0f + exp2f_(gate)), mA, mB);
            const float a1 = dpp_x1(act), a2 = dpp_x2(act), a3 = dpp_x3(act);
            const float p02 = act * a2, p13 = a1 * a3;
            const float ig = gb0 ? p13 : p02;
            const float fv = gb0 ? (gb1 ? a2 : act) : (gb1 ? a3 : a1);
            const float ov = gb0 ? (gb1 ? act : a2) : (gb1 ? a1 : a3);
            c = __builtin_fmaf(fv, c, ig);
            const float th = __builtin_fmaf(
                rcpf_(1.0f + exp2f_((2.0f * L2E) * c)), -2.0f, 1.0f);
            const float h = ov * th;

            hsh[g * 24 + j] = (_Float16)h;           // ds_write_b16
            {
                const uint4 r0 = *(const uint4*)(hsh + g * 24);
                const uint4 r1 = *(const uint4*)(hsh + g * 24 + 8);
                hx[0] = bch2(r0.x); hx[1] = bch2(r0.y);
                hx[2] = bch2(r0.z); hx[3] = bch2(r0.w);
                hx[4] = bch2(r1.x); hx[5] = bch2(r1.y);
                hx[6] = bch2(r1.z); hx[7] = bch2(r1.w);
            }

            if (s < 31) {   // xp for next step (immediate offsets)
                const uint4 u = *(const uint4*)(xc + (s + 1) * 8);
                float pa = fdot2_(wiH[0], bch2(u.x), ebias);
                float pb = fdot2_(wiH[1], bch2(u.y), 0.f);
                pa = fdot2_(wiH[2], bch2(u.z), pa);
                pb = fdot2_(wiH[3], bch2(u.w), pb);
                xp = pa + pb;
            }
        }
        if (chunk + 1 < 16) {
            _Float16* nb = ((chunk + 1) & 1) ? xsB : xsA;
            uint2 p;
            p.x = __builtin_bit_cast(unsigned, h2{(_Float16)pf.x, (_Float16)pf.y});
            p.y = __builtin_bit_cast(unsigned, h2{(_Float16)pf.z, (_Float16)pf.w});
            *(uint2*)(nb + lane * 4) = p;
            if (chunk + 2 < 16) pf = *(const float4*)(xb + (chunk + 2) * 256 + lane * 4);
            const uint4 u = *(const uint4*)(nb);
            float pa = fdot2_(wiH[0], bch2(u.x), ebias);
            float pb = fdot2_(wiH[1], bch2(u.y), 0.f);
            pa = fdot2_(wiH[2], bch2(u.z), pa);
            pb = fdot2_(wiH[3], bch2(u.w), pb);
            xp = pa + pb;
        }
    }

    // ------------- decoder weights + constant input projection -------------
    // hx == h_T here
    float udec;
    {
        float aa = sG * (dbih[r] + dbhh[r]);
        float bb = 0.f;
#pragma unroll
        for (int k = 0; k < 8; k += 2) {
            const h2 wa = h2{(_Float16)(sG * dWih[r * 16 + 2 * k]),
                            (_Float16)(sG * dWih[r * 16 + 2 * k + 1])};
            const h2 wb = h2{(_Float16)(sG * dWih[r * 16 + 2 * k + 2]),
                            (_Float16)(sG * dWih[r * 16 + 2 * k + 3])};
            aa = fdot2_(wa, hx[k], aa);
            bb = fdot2_(wb, hx[k + 1], bb);
        }
        udec = aa + bb;
    }
#pragma unroll
    for (int k = 0; k < 8; ++k)
        wh[k] = h2{(_Float16)(sG * dWhh[r * 16 + 2 * k]),
                   (_Float16)(sG * dWhh[r * 16 + 2 * k + 1])};
    const int ro = lane & 7;
    h2 wo[8];
#pragma unroll
    for (int k = 0; k < 8; ++k)
        wo[k] = h2{(_Float16)oW[ro * 16 + 2 * k], (_Float16)oW[ro * 16 + 2 * k + 1]};
    const float obv = ob[ro];

    hsh[g * 24 + j] = (_Float16)0.f;
#pragma unroll
    for (int p = 0; p < 8; ++p) hx[p] = h2{(_Float16)0.f, (_Float16)0.f};
    c = 0.f;
    float* outp = out + (size_t)chain * (T_ * F_);

    // ---------------- decoder + fused output projection ----------------
#pragma unroll 4
    for (int t = 0; t < T_; ++t) {
        float aa = fdot2_(wh[0], hx[0], udec);
        float bb = fdot2_(wh[1], hx[1], 0.f);
        aa = fdot2_(wh[2], hx[2], aa);
        bb = fdot2_(wh[3], hx[3], bb);
        aa = fdot2_(wh[4], hx[4], aa);
        bb = fdot2_(wh[5], hx[5], bb);
        aa = fdot2_(wh[6], hx[6], aa);
        bb = fdot2_(wh[7], hx[7], bb);
        const float gate = aa + bb;

        const float act = __builtin_fmaf(rcpf_(1.0f + exp2f_(gate)), mA, mB);
        const float a1 = dpp_x1(act), a2 = dpp_x2(act), a3 = dpp_x3(act);
        const float p02 = act * a2, p13 = a1 * a3;
        const float ig = gb0 ? p13 : p02;
        const float fv = gb0 ? (gb1 ? a2 : act) : (gb1 ? a3 : a1);
        const float ov = gb0 ? (gb1 ? act : a2) : (gb1 ? a1 : a3);
        c = __builtin_fmaf(fv, c, ig);
        const float th = __builtin_fmaf(
            rcpf_(1.0f + exp2f_((2.0f * L2E) * c)), -2.0f, 1.0f);
        const float h = ov * th;

        hsh[g * 24 + j] = (_Float16)h;
        {
            const uint4 r0 = *(const uint4*)(hsh + g * 24);
            const uint4 r1 = *(const uint4*)(hsh + g * 24 + 8);
            hx[0] = bch2(r0.x); hx[1] = bch2(r0.y);
            hx[2] = bch2(r0.z); hx[3] = bch2(r0.w);
            hx[4] = bch2(r1.x); hx[5] = bch2(r1.y);
            hx[6] = bch2(r1.z); hx[7] = bch2(r1.w);
        }

        float oa = fdot2_(wo[0], hx[0], obv);
        float obb = fdot2_(wo[1], hx[1], 0.f);
        oa = fdot2_(wo[2], hx[2], oa);
        obb = fdot2_(wo[3], hx[3], obb);
        oa = fdot2_(wo[4], hx[4], oa);
        obb = fdot2_(wo[5], hx[5], obb);
        oa = fdot2_(wo[6], hx[6], oa);
        obb = fdot2_(wo[7], hx[7], obb);
        if (lane < 8) outp[t * F_ + ro] = oa + obb;
    }
}

extern "C" void kernel_launch(void* const* d_in, const int* in_sizes, int n_in,
                              void* d_out, int out_size, void* d_ws, size_t ws_size,
                              hipStream_t stream) {
    (void)in_sizes; (void)n_in; (void)d_ws; (void)ws_size; (void)out_size;
    lstm_ae_w64<<<dim3(B_), dim3(64), 0, stream>>>(
        (const float*)d_in[0],
        (const float*)d_in[1], (const float*)d_in[2],
        (const float*)d_in[3], (const float*)d_in[4],
        (const float*)d_in[5], (const float*)d_in[6],
        (const float*)d_in[7], (const float*)d_in[8],
        (const float*)d_in[9], (const float*)d_in[10],
        (float*)d_out);
}